// Round 9
// baseline (409.018 us; speedup 1.0000x reference)
//
#include <hip/hip_runtime.h>
#include <stdint.h>

// Transformer block: B=64 T=512 C=512 H=16 D=32, FF=2048. fp32 in/out, bf16 MFMA inside.

typedef __attribute__((ext_vector_type(8))) short bf16x8;
typedef __attribute__((ext_vector_type(4))) short bf16x4;
typedef __attribute__((ext_vector_type(4))) float f32x4;

__device__ __forceinline__ unsigned short f2bf(float x) {
  union { float f; unsigned u; } v; v.f = x;
  unsigned r = v.u + 0x7fff + ((v.u >> 16) & 1);   // RNE
  return (unsigned short)(r >> 16);
}

#if __has_builtin(__builtin_amdgcn_exp2f)
__device__ __forceinline__ float exp2fast(float x) { return __builtin_amdgcn_exp2f(x); }
#else
__device__ __forceinline__ float exp2fast(float x) { return exp2f(x); }
#endif

// v_cvt_pk_bf16_f32: lo -> bits[15:0], hi -> bits[31:16] (RNE). No builtin on gfx950.
__device__ __forceinline__ unsigned cvtpk(float lo, float hi) {
  unsigned r; asm("v_cvt_pk_bf16_f32 %0, %1, %2" : "=v"(r) : "v"(lo), "v"(hi)); return r;
}

__device__ __forceinline__ f32x4 MFMA32(bf16x8 a, bf16x8 b, f32x4 c) {
  return __builtin_amdgcn_mfma_f32_16x16x32_bf16(a, b, c, 0, 0, 0);
}

#if __has_builtin(__builtin_amdgcn_mfma_f32_16x16x16bf16_1k)
__device__ __forceinline__ f32x4 MFMA16(bf16x4 a, bf16x4 b, f32x4 c) {
  return __builtin_amdgcn_mfma_f32_16x16x16bf16_1k(a, b, c, 0, 0, 0);
}
#else
__device__ __forceinline__ f32x4 MFMA16(bf16x4 a, bf16x4 b, f32x4 c) {
  f32x4 d;
  asm volatile("v_mfma_f32_16x16x16_bf16 %0, %1, %2, %3\n\ts_nop 7\n\ts_nop 3"
               : "=v"(d) : "v"(a), "v"(b), "v"(c));
  return d;
}
#endif

// global -> LDS direct copy, 16B per lane. LDS dest must be wave-uniform base;
// HW writes base + lane*16. Global src is per-lane.
__device__ __forceinline__ void gload_lds16(const void* g, void* l) {
  __builtin_amdgcn_global_load_lds(
      (const __attribute__((address_space(1))) unsigned int*)(uintptr_t)g,
      (__attribute__((address_space(3))) unsigned int*)(unsigned)(uintptr_t)l,
      16, 0, 0);
}

#define WAITV8() do { asm volatile("s_waitcnt vmcnt(8)" ::: "memory"); } while (0)
#define WAITV0() do { asm volatile("s_waitcnt vmcnt(0)" ::: "memory"); } while (0)
#define WAITL(N) do { asm volatile("s_waitcnt lgkmcnt(" #N ")" ::: "memory"); } while (0)
#define SBAR()   __builtin_amdgcn_s_barrier()
#define SCHED0() __builtin_amdgcn_sched_barrier(0)
#define PRIO1()  __builtin_amdgcn_s_setprio(1)
#define PRIO0()  __builtin_amdgcn_s_setprio(0)

// ---------------- weight prep (LDS-tiled, coalesced both sides) ----------------
// dst[n][k] = W{q,k,v}[h][k][d], n = q*512 + h*32 + d. Block = (q,h,ktile of 64).
__global__ __launch_bounds__(256) void prep_qkv_w(
    const float* __restrict__ Wq, const float* __restrict__ Wk,
    const float* __restrict__ Wv, unsigned short* __restrict__ dst)
{
  __shared__ float tile[64 * 33];            // 64 k-rows x 32 d, pad 33
  const int b = blockIdx.x;                  // 3*16*8 = 384
  const int q = b / 128, hh = (b >> 3) & 15, kt = (b & 7) << 6;
  const float* W = (q == 0) ? Wq : ((q == 1) ? Wk : Wv);
  const int t = threadIdx.x;
  const int rr = t >> 2, ch = (t & 3) << 3;  // read: row, 8-float chunk
  const float* sp = W + ((size_t)hh * 512 + kt + rr) * 32 + ch;
  float4 v0 = *(const float4*)(sp), v1 = *(const float4*)(sp + 4);
  float* dp = &tile[rr * 33 + ch];
  dp[0] = v0.x; dp[1] = v0.y; dp[2] = v0.z; dp[3] = v0.w;
  dp[4] = v1.x; dp[5] = v1.y; dp[6] = v1.z; dp[7] = v1.w;
  __syncthreads();
  const int d = t >> 3, toct = (t & 7) << 3; // write: d-row, 8 k-elems
  bf16x8 o;
#pragma unroll
  for (int j = 0; j < 8; ++j) o[j] = (short)f2bf(tile[(toct + j) * 33 + d]);
  *(bf16x8*)(dst + ((size_t)q * 512 + hh * 32 + d) * 512 + kt + toct) = o;
}

// dst (Nd x Kd bf16) = transpose of src (Kd x Nd fp32). 64x64 tiles via LDS.
__global__ __launch_bounds__(256) void transpose_cast(
    const float* __restrict__ src, unsigned short* __restrict__ dst, int Kd, int Nd)
{
  __shared__ float tile[64 * 65];
  const int nk = Kd >> 6;
  const int kt = (blockIdx.x % nk) << 6, nt = (blockIdx.x / nk) << 6;
  const int t = threadIdx.x;
  const int rr = t >> 2, ch = (t & 3) << 4;  // read: k-row, 16-float chunk
  const float* sp = src + (size_t)(kt + rr) * Nd + nt + ch;
  float* dp = &tile[rr * 65 + ch];
#pragma unroll
  for (int c = 0; c < 4; ++c) {
    float4 v = *(const float4*)(sp + c * 4);
    dp[c * 4 + 0] = v.x; dp[c * 4 + 1] = v.y; dp[c * 4 + 2] = v.z; dp[c * 4 + 3] = v.w;
  }
  __syncthreads();
  const int nn = t >> 2, c2 = (t & 3) << 4;  // write: n-row, 16 k-elems
  bf16x8 o0, o1;
#pragma unroll
  for (int j = 0; j < 8; ++j) {
    o0[j] = (short)f2bf(tile[(c2 + j) * 65 + nn]);
    o1[j] = (short)f2bf(tile[(c2 + 8 + j) * 65 + nn]);
  }
  unsigned short* op = dst + (size_t)(nt + nn) * Kd + kt + c2;
  *(bf16x8*)(op) = o0;
  *(bf16x8*)(op + 8) = o1;
}

// ---------------- layernorm (fp32 in -> bf16 out), one wave per 512-row ----------------
__global__ __launch_bounds__(256) void ln_kernel(
    const float* __restrict__ x, const float* __restrict__ g,
    const float* __restrict__ b, unsigned short* __restrict__ out)
{
  const int lane = threadIdx.x & 63;
  const size_t row = (size_t)blockIdx.x * 4 + (threadIdx.x >> 6);
  const float* xp = x + row * 512 + lane * 8;
  float xv[8] __attribute__((aligned(16)));
  *(float4*)(xv)     = *(const float4*)(xp);
  *(float4*)(xv + 4) = *(const float4*)(xp + 4);
  float s = 0.f, s2 = 0.f;
#pragma unroll
  for (int j = 0; j < 8; ++j) { s += xv[j]; s2 += xv[j] * xv[j]; }
#pragma unroll
  for (int m = 1; m < 64; m <<= 1) { s += __shfl_xor(s, m); s2 += __shfl_xor(s2, m); }
  float mean = s * (1.f / 512.f);
  float rstd = rsqrtf(fmaxf(s2 * (1.f / 512.f) - mean * mean, 0.f) + 1e-5f);
  float gv[8] __attribute__((aligned(16))), bv[8] __attribute__((aligned(16)));
  *(float4*)(gv)     = *(const float4*)(g + lane * 8);
  *(float4*)(gv + 4) = *(const float4*)(g + lane * 8 + 4);
  *(float4*)(bv)     = *(const float4*)(b + lane * 8);
  *(float4*)(bv + 4) = *(const float4*)(b + lane * 8 + 4);
  bf16x8 o;
#pragma unroll
  for (int j = 0; j < 8; ++j) o[j] = (short)f2bf((xv[j] - mean) * rstd * gv[j] + bv[j]);
  *(bf16x8*)(out + row * 512 + lane * 8) = o;
}

// ---------------- V transpose: [B][H][T][D] -> [B][H][D][T], LDS-tiled ----------------
__global__ __launch_bounds__(256) void vt_kernel(
    const unsigned short* __restrict__ vnat, unsigned short* __restrict__ vt)
{
  __shared__ unsigned short tile[64 * 36];   // 64 t-rows x 32 d, padded to 36
  const int bh = blockIdx.x >> 3, tt = (blockIdx.x & 7) << 6;
  const int tid = threadIdx.x;
  const int rr = tid >> 2, ch = tid & 3;     // read: (t-row, 8-elem d-chunk)
  bf16x8 v = *(const bf16x8*)(vnat + ((size_t)bh * 512 + tt + rr) * 32 + ch * 8);
  unsigned short* dst = &tile[rr * 36 + ch * 8];
#pragma unroll
  for (int j = 0; j < 8; ++j) dst[j] = (unsigned short)v[j];
  __syncthreads();
  const int d = tid >> 3, toct = (tid & 7) << 3;  // write: (d-row, 8-elem t-chunk)
  union { unsigned short s[8]; bf16x8 v8; } o;
#pragma unroll
  for (int j = 0; j < 8; ++j) o.s[j] = tile[(toct + j) * 36 + d];
  *(bf16x8*)(vt + ((size_t)bh * 32 + d) * 512 + tt + toct) = o.v8;
}

// ---------------- persistent 256x256 GEMM, fragment-pipelined (counted lgkm) -------
// Grid MUST be 256. 8 waves (2Mx4N), per-wave C 128x64; BK=64; 2 K-tile LDS dbuf.
// T4 on BOTH counters: vmcnt(8) for staging, counted lgkmcnt for fragments:
//   entry: af,bfa of tile g in flight (12 reads).
//   P1: issue bfb(4);  lgkmcnt(4)  -> q(0,0)        [entry drained, bfb out]
//   P2: issue ag(8);   lgkmcnt(8)  -> q(0,1)        [bfb drained, ag out]
//   P3:                lgkmcnt(0)  -> q(1,0)
//   SBAR (all cur reads done) ; STAGE(g+2) into cur ; vmcnt(8) (or vmcnt(0) at tail:
//   last tile's DMA must drain before its buffer is read -- round-8 race fix) ;
//   SBAR (nxt visible) ; issue af',bfa' from nxt ; q(1,1) runs under them.
// MODE 1: QKV scatter (Q,K -> obf [2][B][H][T][D], Q scaled; V -> vout natural)
// MODE 2: out fp32 = acc + bias[col] + resid[row*N+col]
// MODE 3: out bf16 = relu(acc + bias[col])
template <int MODE, int P, int KT, int NBY>
__device__ __forceinline__ void gemm_persist(
    const unsigned short* __restrict__ A, const unsigned short* __restrict__ Bt,
    int N,
    unsigned short* __restrict__ obf, float* __restrict__ of32,
    const float* __restrict__ bias, const float* __restrict__ resid,
    unsigned short* __restrict__ vout)
{
  constexpr int K = KT * 64;
  constexpr int TOT = P * KT;
  __shared__ __align__(16) unsigned short As[2][256 * 64];
  __shared__ __align__(16) unsigned short Bs[2][256 * 64];
  const int tid = threadIdx.x, lane = tid & 63, wid = tid >> 6;
  const int wr = wid >> 2, wc = wid & 3;
  const int r = lane & 15, hq = lane >> 4;

  // XCD-chunked persistent tile list: block b -> tau0 = (b%8)*32P + (b/8)*P
  const int tau0 = (blockIdx.x & 7) * (32 * P) + (blockIdx.x >> 3) * P;

  const int srow = wid * 32 + (lane >> 3);
  const int schunk = ((lane & 7) ^ ((lane >> 3) & 7)) * 8;  // element offset in [0,64)

  auto STAGE_A = [&](int g2) {
    const int m2 = g2 / KT, kt2 = g2 % KT;
    const int bx = (tau0 + m2) / NBY;
    const unsigned short* src = A + (size_t)(bx * 256 + srow) * K + kt2 * 64 + schunk;
    char* dst = (char*)(&As[g2 & 1][0]) + wid * 4096;
#pragma unroll
    for (int g = 0; g < 4; ++g) gload_lds16(src + (size_t)g * 8 * K, dst + g * 1024);
  };
  auto STAGE_B = [&](int g2) {
    const int m2 = g2 / KT, kt2 = g2 % KT;
    const int tau = tau0 + m2;
    const int by = tau - (tau / NBY) * NBY;
    const unsigned short* src = Bt + (size_t)(by * 256 + srow) * K + kt2 * 64 + schunk;
    char* dst = (char*)(&Bs[g2 & 1][0]) + wid * 4096;
#pragma unroll
    for (int g = 0; g < 4; ++g) gload_lds16(src + (size_t)g * 8 * K, dst + g * 1024);
  };

  // ds_read addressing: byte = row*128 + ((chunk ^ (row&7))*16), chunk = kk*4+hq
  const int x0 = ((hq) ^ (r & 7)) * 16;
  const int x1 = ((4 + hq) ^ (r & 7)) * 16;
  const int abase = (wr * 128 + r) * 128;
  const int bbase = (wc * 64 + r) * 128;

  f32x4 acc[8][4] = {};
  bf16x8 af[4][2], ag[4][2], bfa[2][2], bfb[2][2];

  auto LOAD_ENTRY = [&](const char* Ab, const char* Bb) {  // af (8) + bfa (4)
#pragma unroll
    for (int m2 = 0; m2 < 4; ++m2) {
      af[m2][0] = *(const bf16x8*)(Ab + abase + m2 * 2048 + x0);
      af[m2][1] = *(const bf16x8*)(Ab + abase + m2 * 2048 + x1);
    }
#pragma unroll
    for (int n2 = 0; n2 < 2; ++n2) {
      bfa[n2][0] = *(const bf16x8*)(Bb + bbase + n2 * 2048 + x0);
      bfa[n2][1] = *(const bf16x8*)(Bb + bbase + n2 * 2048 + x1);
    }
  };

  STAGE_A(0); STAGE_B(0);
  STAGE_A(1); STAGE_B(1);
  WAITV8(); SCHED0();
  SBAR();
  LOAD_ENTRY((const char*)(&As[0][0]), (const char*)(&Bs[0][0]));  // 12 in flight
  SCHED0();

#pragma unroll 1
  for (int p = 0; p < P; ++p) {
#pragma unroll 2
    for (int t = 0; t < KT; ++t) {
      const int g = p * KT + t;
      const int g2 = g + 2;
      const char* Ab = (const char*)(&As[g & 1][0]);
      const char* Bb = (const char*)(&Bs[g & 1][0]);
      const char* An = (const char*)(&As[(g + 1) & 1][0]);
      const char* Bn = (const char*)(&Bs[(g + 1) & 1][0]);
      // ---- P1: issue bfb; wait entry(af,bfa); MFMA q(0,0)
#pragma unroll
      for (int n2 = 0; n2 < 2; ++n2) {
        bfb[n2][0] = *(const bf16x8*)(Bb + bbase + (n2 + 2) * 2048 + x0);
        bfb[n2][1] = *(const bf16x8*)(Bb + bbase + (n2 + 2) * 2048 + x1);
      }
      SCHED0();
      WAITL(4); SCHED0();
      PRIO1();
#pragma unroll
      for (int m = 0; m < 4; ++m)
#pragma unroll
        for (int n = 0; n < 2; ++n) {
          acc[m][n] = MFMA32(af[m][0], bfa[n][0], acc[m][n]);
          acc[m][n] = MFMA32(af[m][1], bfa[n][1], acc[m][n]);
        }
      PRIO0();
      // ---- P2: issue ag (A half1); wait bfb; MFMA q(0,1)
#pragma unroll
      for (int m2 = 0; m2 < 4; ++m2) {
        ag[m2][0] = *(const bf16x8*)(Ab + abase + 8192 + m2 * 2048 + x0);
        ag[m2][1] = *(const bf16x8*)(Ab + abase + 8192 + m2 * 2048 + x1);
      }
      SCHED0();
      WAITL(8); SCHED0();
      PRIO1();
#pragma unroll
      for (int m = 0; m < 4; ++m)
#pragma unroll
        for (int n = 0; n < 2; ++n) {
          acc[m][n + 2] = MFMA32(af[m][0], bfb[n][0], acc[m][n + 2]);
          acc[m][n + 2] = MFMA32(af[m][1], bfb[n][1], acc[m][n + 2]);
        }
      PRIO0();
      // ---- P3: wait ag; MFMA q(1,0)
      WAITL(0); SCHED0();
      PRIO1();
#pragma unroll
      for (int m = 0; m < 4; ++m)
#pragma unroll
        for (int n = 0; n < 2; ++n) {
          acc[4 + m][n] = MFMA32(ag[m][0], bfa[n][0], acc[4 + m][n]);
          acc[4 + m][n] = MFMA32(ag[m][1], bfa[n][1], acc[4 + m][n]);
        }
      PRIO0();
      SBAR();                                // all cur reads complete block-wide
      if (g2 < TOT) {
        STAGE_B(g2); STAGE_A(g2);
        WAITV8();                            // tile g+1 drained; g+2 stays in flight
      } else {
        WAITV0();                            // tail: drain last tile's DMA (r8 fix)
      }
      SCHED0();
      SBAR();                                // nxt buffer staged & visible
      if (g + 1 < TOT) {                     // prefetch next tile's entry frags
        LOAD_ENTRY(An, Bn);
        SCHED0();
      }
      // ---- P4: MFMA q(1,1) under the 12 entry reads
      PRIO1();
#pragma unroll
      for (int m = 0; m < 4; ++m)
#pragma unroll
        for (int n = 0; n < 2; ++n) {
          acc[4 + m][n + 2] = MFMA32(ag[m][0], bfb[n][0], acc[4 + m][n + 2]);
          acc[4 + m][n + 2] = MFMA32(ag[m][1], bfb[n][1], acc[4 + m][n + 2]);
        }
      PRIO0();
    }

    // ---- macro epilogue (regs -> global only; next-macro pipeline in flight)
    {
      const int tau = tau0 + p;
      const int bx = tau / NBY, by = tau - bx * NBY;
      const int brow = bx << 8, bcol = by << 8;
#pragma unroll
      for (int m = 0; m < 8; ++m)
#pragma unroll
        for (int n = 0; n < 4; ++n) {
          const int row0 = brow + wr * 128 + m * 16 + hq * 4;
          const int col = bcol + wc * 64 + n * 16 + r;
#pragma unroll
          for (int q2 = 0; q2 < 4; ++q2) {
            const int row = row0 + q2;
            float v = acc[m][n][q2];
            if (MODE == 1) {
              const int which = col >> 9, hh = (col >> 5) & 15, dd = col & 31;
              const int bb = row >> 9, tt = row & 511;
              const size_t off = ((((size_t)bb) * 16 + hh) * 512 + tt) * 32 + dd;
              if (which < 2) {
                if (which == 0) v *= 0.25503521f;  // (1/sqrt(32)) * log2(e)
                obf[(size_t)which * 16777216 + off] = f2bf(v);
              } else
                vout[off] = f2bf(v);
            } else if (MODE == 2) {
              v += bias[col] + resid[(size_t)row * N + col];
              of32[(size_t)row * N + col] = v;
            } else if (MODE == 3) {
              v = fmaxf(v + bias[col], 0.f);
              obf[(size_t)row * N + col] = f2bf(v);
            }
            acc[m][n][q2] = 0.f;
          }
        }
    }
  }
}

// distinct names per call site for rocprof attribution; grid must be 256
__global__ __launch_bounds__(512, 2) void qkv_gemm(
    const unsigned short* __restrict__ A, const unsigned short* __restrict__ Bt,
    unsigned short* __restrict__ obf, unsigned short* __restrict__ vout)
{ gemm_persist<1, 3, 8, 6>(A, Bt, 1536, obf, nullptr, nullptr, nullptr, vout); }

__global__ __launch_bounds__(512, 2) void proj_gemm(
    const unsigned short* __restrict__ A, const unsigned short* __restrict__ Bt,
    float* __restrict__ of32, const float* __restrict__ bias,
    const float* __restrict__ resid)
{ gemm_persist<2, 1, 8, 2>(A, Bt, 512, nullptr, of32, bias, resid, nullptr); }

__global__ __launch_bounds__(512, 2) void ffn1_gemm(
    const unsigned short* __restrict__ A, const unsigned short* __restrict__ Bt,
    unsigned short* __restrict__ obf, const float* __restrict__ bias)
{ gemm_persist<3, 4, 8, 8>(A, Bt, 2048, obf, nullptr, bias, nullptr, nullptr); }

__global__ __launch_bounds__(512, 2) void ffn2_gemm(
    const unsigned short* __restrict__ A, const unsigned short* __restrict__ Bt,
    float* __restrict__ of32, const float* __restrict__ bias,
    const float* __restrict__ resid)
{ gemm_persist<2, 1, 32, 2>(A, Bt, 512, nullptr, of32, bias, resid, nullptr); }

// ---------------- causal attention: one block per (b,h), 8 waves ----------------
// Swapped QK^T: S^T = mfma(K_frag, Q_frag) so each lane owns one q-column with
// keys lane-local (k = 4*hq + j per 16-key tile). Softmax: in-lane tree + 2 shfl_xor.
// P feeds PV (16x16x16 MFMA) directly via cvt_pk -> no LDS round-trip.
// Scores arrive pre-scaled by (1/sqrt(32))*log2(e); exp = v_exp_f32 (2^x).
// Qb,Kb: [B][H][T][D] bf16 ; Vt: [B][H][D][T] bf16 ; att: [B*T][512] bf16 (col h*32+d)
__global__ __launch_bounds__(512, 4) void attn_kernel(
    const unsigned short* __restrict__ Qb, const unsigned short* __restrict__ Kb,
    const unsigned short* __restrict__ Vt, unsigned short* __restrict__ att)
{
  __shared__ __align__(16) unsigned short Ks[512 * 32];  // 32 KB, linear [t][d]
  __shared__ __align__(16) unsigned short Vs[32 * 512];  // 32 KB, [d][t], 16B-blk ^ (d&15)
  const int tid = threadIdx.x, lane = tid & 63, wid = tid >> 6;
  const int bh = blockIdx.x;
  const int r = lane & 15, hq = lane >> 4;
  const unsigned short* Kg = Kb + (size_t)bh * (512 * 32);
  const unsigned short* Vg = Vt + (size_t)bh * (32 * 512);
#pragma unroll
  for (int it = 0; it < 4; ++it) {
    const int c = it * 512 + tid;
    gload_lds16(Kg + c * 8, (char*)Ks + (it * 512 + wid * 64) * 16);
    const int d = c >> 6, sb = c & 63;
    gload_lds16(Vg + d * 512 + (sb ^ (d & 15)) * 8, (char*)Vs + (it * 512 + wid * 64) * 16);
  }
  __syncthreads();

  const f32x4 z = {0.f, 0.f, 0.f, 0.f};
  for (int p = 0; p < 4; ++p) {
    // balanced triangular tile pairing: waves get tiles {w, 15-w, 16+w, 31-w}
    const int t0 = (((p >> 1) << 4) + ((p & 1) ? 15 - wid : wid)) << 4;
    const bf16x8 qf = *(const bf16x8*)(Qb + ((size_t)bh * 512 + t0 + r) * 32 + hq * 8);
    f32x4 o0 = z, o1 = z;
    float m = -1e30f, l = 0.f;
    const int s0m = t0 & ~31;
    for (int s0 = 0; s0 <= s0m; s0 += 32) {
      f32x4 st0 = MFMA32(*(const bf16x8*)((const char*)Ks + (s0 + r) * 64 + hq * 16), qf, z);
      f32x4 st1 = MFMA32(*(const bf16x8*)((const char*)Ks + (s0 + 16 + r) * 64 + hq * 16), qf, z);
      if (s0 == s0m) {                       // only the diagonal chunk needs masking
        const int qq = t0 + r;
#pragma unroll
        for (int j = 0; j < 4; ++j) {
          if (s0 + 4 * hq + j > qq)      st0[j] = -1e30f;
          if (s0 + 16 + 4 * hq + j > qq) st1[j] = -1e30f;
        }
      }
      float mx = fmaxf(fmaxf(fmaxf(st0[0], st0[1]), fmaxf(st0[2], st0[3])),
                       fmaxf(fmaxf(st1[0], st1[1]), fmaxf(st1[2], st1[3])));
      mx = fmaxf(mx, __shfl_xor(mx, 16));
      mx = fmaxf(mx, __shfl_xor(mx, 32));
      if (!__all(mx <= m + 8.f)) {           // defer-max (T13), THR=8 in log2 domain
        const float mn = fmaxf(m, mx);
        const float f = exp2fast(m - mn);
        m = mn; l *= f; o0 *= f; o1 *= f;
      }
      float p0[4], p1[4];
#pragma unroll
      for (int j = 0; j < 4; ++j) {
        p0[j] = exp2fast(st0[j] - m);
        p1[j] = exp2fast(st1[j] - m);
      }
      float rs = ((p0[0] + p0[1]) + (p0[2] + p0[3])) + ((p1[0] + p1[1]) + (p1[2] + p1[3]));
      rs += __shfl_xor(rs, 16);
      rs += __shfl_xor(rs, 32);
      l += rs;
      union { unsigned u[2]; bf16x4 v; } a0, a1;
      a0.u[0] = cvtpk(p0[0], p0[1]); a0.u[1] = cvtpk(p0[2], p0[3]);
      a1.u[0] = cvtpk(p1[0], p1[1]); a1.u[1] = cvtpk(p1[2], p1[3]);
      const int lb = (s0 >> 3) + (hq >> 1);
      const char* vb = (const char*)Vs + (hq & 1) * 8;
      o0 = MFMA16(a0.v, *(const bf16x4*)(vb + r * 1024 + ((lb) ^ r) * 16), o0);
      o0 = MFMA16(a1.v, *(const bf16x4*)(vb + r * 1024 + ((lb + 2) ^ r) * 16), o0);
      o1 = MFMA16(a0.v, *(const bf16x4*)(vb + (r + 16) * 1024 + ((lb) ^ r) * 16), o1);
      o1 = MFMA16(a1.v, *(const bf16x4*)(vb + (r + 16) * 1024 + ((lb + 2) ^ r) * 16), o1);
    }
    // O ownership: d = r (o0) / 16+r (o1), q = t0 + 4*hq + j. l lives on lanes keyed by
    // r == q_rel (all 4 hq copies equal after the xor-reduce) -> shfl to fetch.
    const size_t ob = ((size_t)(bh >> 4) * 512) * 512 + (size_t)((bh & 15) * 32);
#pragma unroll
    for (int j = 0; j < 4; ++j) {
      const float li = 1.f / __shfl(l, 4 * hq + j);
      const size_t rowb = ob + (size_t)(t0 + 4 * hq + j) * 512;
      att[rowb + r]      = f2bf(o0[j] * li);
      att[rowb + 16 + r] = f2bf(o1[j] * li);
    }
  }
}

// ---------------- launcher ----------------
extern "C" void kernel_launch(void* const* d_in, const int* in_sizes, int n_in,
                              void* d_out, int out_size, void* d_ws, size_t ws_size,
                              hipStream_t stream)
{
  const float* x   = (const float*)d_in[0];
  const float* Wq  = (const float*)d_in[1];
  const float* Wk  = (const float*)d_in[2];
  const float* Wv  = (const float*)d_in[3];
  const float* Wp  = (const float*)d_in[4];
  const float* bp  = (const float*)d_in[5];
  const float* W1  = (const float*)d_in[6];
  const float* b1  = (const float*)d_in[7];
  const float* W2  = (const float*)d_in[8];
  const float* b2  = (const float*)d_in[9];
  const float* g1  = (const float*)d_in[10];
  const float* bb1 = (const float*)d_in[11];
  const float* g2  = (const float*)d_in[12];
  const float* bb2 = (const float*)d_in[13];
  float* out = (float*)d_out;

  char* ws = (char*)d_ws;
  // layout (bytes):
  unsigned short* h    = (unsigned short*)(ws);               // 32 MB (h, then reused as h2)
  unsigned short* wqkv = (unsigned short*)(ws + 33554432);    // 1.5 MB (1536 x 512)
  unsigned short* wp   = (unsigned short*)(ws + 35127296);    // 0.5 MB (512 x 512)
  unsigned short* w1   = (unsigned short*)(ws + 35651584);    // 2 MB (2048 x 512)
  unsigned short* w2   = (unsigned short*)(ws + 37748736);    // 2 MB (512 x 2048)
  unsigned short* qk   = (unsigned short*)(ws + 39845888);    // 64 MB: Q then K [B][H][T][D]
  unsigned short* vt   = qk + (size_t)2 * 16777216;           // 32 MB: V^T [B][H][D][T]
  unsigned short* att  = vt + 16777216;                       // 32 MB: attn out / V-natural
  unsigned short* vnat = att;                                 // V [B][H][T][D] staging
  unsigned short* mid  = qk;                                  // 128 MB alias over qk+vt+att
  if (ws_size < 174063616) return;  // insufficient workspace -> visible failure

  prep_qkv_w<<<384, 256, 0, stream>>>(Wq, Wk, Wv, wqkv);
  transpose_cast<<<64, 256, 0, stream>>>(Wp, wp, 512, 512);
  transpose_cast<<<256, 256, 0, stream>>>(W1, w1, 512, 2048);
  transpose_cast<<<256, 256, 0, stream>>>(W2, w2, 2048, 512);

  ln_kernel<<<8192, 256, 0, stream>>>(x, g1, bb1, h);

  qkv_gemm<<<256, 512, 0, stream>>>(h, wqkv, qk, vnat);

  vt_kernel<<<8192, 256, 0, stream>>>(vnat, vt);

  attn_kernel<<<1024, 512, 0, stream>>>(qk, qk + 16777216, vt, att);

  proj_gemm<<<256, 512, 0, stream>>>(att, wp, out, bp, x);

  ln_kernel<<<8192, 256, 0, stream>>>(out, g2, bb2, h);

  ffn1_gemm<<<256, 512, 0, stream>>>(h, w1, mid, b1);

  ffn2_gemm<<<256, 512, 0, stream>>>(mid, w2, out, b2, out);
}

// Round 10
// 384.260 us; speedup vs baseline: 1.0644x; 1.0644x over previous
//
#include <hip/hip_runtime.h>
#include <stdint.h>

// Transformer block: B=64 T=512 C=512 H=16 D=32, FF=2048. fp32 in/out, bf16 MFMA inside.

typedef __attribute__((ext_vector_type(8))) short bf16x8;
typedef __attribute__((ext_vector_type(4))) short bf16x4;
typedef __attribute__((ext_vector_type(4))) float f32x4;

__device__ __forceinline__ unsigned short f2bf(float x) {
  union { float f; unsigned u; } v; v.f = x;
  unsigned r = v.u + 0x7fff + ((v.u >> 16) & 1);   // RNE
  return (unsigned short)(r >> 16);
}

#if __has_builtin(__builtin_amdgcn_exp2f)
__device__ __forceinline__ float exp2fast(float x) { return __builtin_amdgcn_exp2f(x); }
#else
__device__ __forceinline__ float exp2fast(float x) { return exp2f(x); }
#endif

// v_cvt_pk_bf16_f32: lo -> bits[15:0], hi -> bits[31:16] (RNE). No builtin on gfx950.
__device__ __forceinline__ unsigned cvtpk(float lo, float hi) {
  unsigned r; asm("v_cvt_pk_bf16_f32 %0, %1, %2" : "=v"(r) : "v"(lo), "v"(hi)); return r;
}

__device__ __forceinline__ f32x4 MFMA32(bf16x8 a, bf16x8 b, f32x4 c) {
  return __builtin_amdgcn_mfma_f32_16x16x32_bf16(a, b, c, 0, 0, 0);
}

#if __has_builtin(__builtin_amdgcn_mfma_f32_16x16x16bf16_1k)
__device__ __forceinline__ f32x4 MFMA16(bf16x4 a, bf16x4 b, f32x4 c) {
  return __builtin_amdgcn_mfma_f32_16x16x16bf16_1k(a, b, c, 0, 0, 0);
}
#else
__device__ __forceinline__ f32x4 MFMA16(bf16x4 a, bf16x4 b, f32x4 c) {
  f32x4 d;
  asm volatile("v_mfma_f32_16x16x16_bf16 %0, %1, %2, %3\n\ts_nop 7\n\ts_nop 3"
               : "=v"(d) : "v"(a), "v"(b), "v"(c));
  return d;
}
#endif

// global -> LDS direct copy, 16B per lane. LDS dest must be wave-uniform base;
// HW writes base + lane*16. Global src is per-lane.
__device__ __forceinline__ void gload_lds16(const void* g, void* l) {
  __builtin_amdgcn_global_load_lds(
      (const __attribute__((address_space(1))) unsigned int*)(uintptr_t)g,
      (__attribute__((address_space(3))) unsigned int*)(unsigned)(uintptr_t)l,
      16, 0, 0);
}

#define WAITVN(N) do { asm volatile("s_waitcnt vmcnt(" #N ")" ::: "memory"); } while (0)
#define WAITV0() do { asm volatile("s_waitcnt vmcnt(0)" ::: "memory"); } while (0)
#define WAITL(N) do { asm volatile("s_waitcnt lgkmcnt(" #N ")" ::: "memory"); } while (0)
#define SBAR()   __builtin_amdgcn_s_barrier()
#define SCHED0() __builtin_amdgcn_sched_barrier(0)
#define PRIO1()  __builtin_amdgcn_s_setprio(1)
#define PRIO0()  __builtin_amdgcn_s_setprio(0)

// ---------------- weight prep (LDS-tiled, coalesced both sides) ----------------
// dst[n][k] = W{q,k,v}[h][k][d], n = q*512 + h*32 + d. Block = (q,h,ktile of 64).
__global__ __launch_bounds__(256) void prep_qkv_w(
    const float* __restrict__ Wq, const float* __restrict__ Wk,
    const float* __restrict__ Wv, unsigned short* __restrict__ dst)
{
  __shared__ float tile[64 * 33];            // 64 k-rows x 32 d, pad 33
  const int b = blockIdx.x;                  // 3*16*8 = 384
  const int q = b / 128, hh = (b >> 3) & 15, kt = (b & 7) << 6;
  const float* W = (q == 0) ? Wq : ((q == 1) ? Wk : Wv);
  const int t = threadIdx.x;
  const int rr = t >> 2, ch = (t & 3) << 3;  // read: row, 8-float chunk
  const float* sp = W + ((size_t)hh * 512 + kt + rr) * 32 + ch;
  float4 v0 = *(const float4*)(sp), v1 = *(const float4*)(sp + 4);
  float* dp = &tile[rr * 33 + ch];
  dp[0] = v0.x; dp[1] = v0.y; dp[2] = v0.z; dp[3] = v0.w;
  dp[4] = v1.x; dp[5] = v1.y; dp[6] = v1.z; dp[7] = v1.w;
  __syncthreads();
  const int d = t >> 3, toct = (t & 7) << 3; // write: d-row, 8 k-elems
  bf16x8 o;
#pragma unroll
  for (int j = 0; j < 8; ++j) o[j] = (short)f2bf(tile[(toct + j) * 33 + d]);
  *(bf16x8*)(dst + ((size_t)q * 512 + hh * 32 + d) * 512 + kt + toct) = o;
}

// dst (Nd x Kd bf16) = transpose of src (Kd x Nd fp32). 64x64 tiles via LDS.
__global__ __launch_bounds__(256) void transpose_cast(
    const float* __restrict__ src, unsigned short* __restrict__ dst, int Kd, int Nd)
{
  __shared__ float tile[64 * 65];
  const int nk = Kd >> 6;
  const int kt = (blockIdx.x % nk) << 6, nt = (blockIdx.x / nk) << 6;
  const int t = threadIdx.x;
  const int rr = t >> 2, ch = (t & 3) << 4;  // read: k-row, 16-float chunk
  const float* sp = src + (size_t)(kt + rr) * Nd + nt + ch;
  float* dp = &tile[rr * 65 + ch];
#pragma unroll
  for (int c = 0; c < 4; ++c) {
    float4 v = *(const float4*)(sp + c * 4);
    dp[c * 4 + 0] = v.x; dp[c * 4 + 1] = v.y; dp[c * 4 + 2] = v.z; dp[c * 4 + 3] = v.w;
  }
  __syncthreads();
  const int nn = t >> 2, c2 = (t & 3) << 4;  // write: n-row, 16 k-elems
  bf16x8 o0, o1;
#pragma unroll
  for (int j = 0; j < 8; ++j) {
    o0[j] = (short)f2bf(tile[(c2 + j) * 65 + nn]);
    o1[j] = (short)f2bf(tile[(c2 + 8 + j) * 65 + nn]);
  }
  unsigned short* op = dst + (size_t)(nt + nn) * Kd + kt + c2;
  *(bf16x8*)(op) = o0;
  *(bf16x8*)(op + 8) = o1;
}

// ---------------- layernorm (fp32 in -> bf16 out), one wave per 512-row ----------------
__global__ __launch_bounds__(256) void ln_kernel(
    const float* __restrict__ x, const float* __restrict__ g,
    const float* __restrict__ b, unsigned short* __restrict__ out)
{
  const int lane = threadIdx.x & 63;
  const size_t row = (size_t)blockIdx.x * 4 + (threadIdx.x >> 6);
  const float* xp = x + row * 512 + lane * 8;
  float xv[8] __attribute__((aligned(16)));
  *(float4*)(xv)     = *(const float4*)(xp);
  *(float4*)(xv + 4) = *(const float4*)(xp + 4);
  float s = 0.f, s2 = 0.f;
#pragma unroll
  for (int j = 0; j < 8; ++j) { s += xv[j]; s2 += xv[j] * xv[j]; }
#pragma unroll
  for (int m = 1; m < 64; m <<= 1) { s += __shfl_xor(s, m); s2 += __shfl_xor(s2, m); }
  float mean = s * (1.f / 512.f);
  float rstd = rsqrtf(fmaxf(s2 * (1.f / 512.f) - mean * mean, 0.f) + 1e-5f);
  float gv[8] __attribute__((aligned(16))), bv[8] __attribute__((aligned(16)));
  *(float4*)(gv)     = *(const float4*)(g + lane * 8);
  *(float4*)(gv + 4) = *(const float4*)(g + lane * 8 + 4);
  *(float4*)(bv)     = *(const float4*)(b + lane * 8);
  *(float4*)(bv + 4) = *(const float4*)(b + lane * 8 + 4);
  bf16x8 o;
#pragma unroll
  for (int j = 0; j < 8; ++j) o[j] = (short)f2bf((xv[j] - mean) * rstd * gv[j] + bv[j]);
  *(bf16x8*)(out + row * 512 + lane * 8) = o;
}

// ---------------- V transpose: [B][H][T][D] -> [B][H][D][T], LDS-tiled ----------------
__global__ __launch_bounds__(256) void vt_kernel(
    const unsigned short* __restrict__ vnat, unsigned short* __restrict__ vt)
{
  __shared__ unsigned short tile[64 * 36];   // 64 t-rows x 32 d, padded to 36
  const int bh = blockIdx.x >> 3, tt = (blockIdx.x & 7) << 6;
  const int tid = threadIdx.x;
  const int rr = tid >> 2, ch = tid & 3;     // read: (t-row, 8-elem d-chunk)
  bf16x8 v = *(const bf16x8*)(vnat + ((size_t)bh * 512 + tt + rr) * 32 + ch * 8);
  unsigned short* dst = &tile[rr * 36 + ch * 8];
#pragma unroll
  for (int j = 0; j < 8; ++j) dst[j] = (unsigned short)v[j];
  __syncthreads();
  const int d = tid >> 3, toct = (tid & 7) << 3;  // write: (d-row, 8-elem t-chunk)
  union { unsigned short s[8]; bf16x8 v8; } o;
#pragma unroll
  for (int j = 0; j < 8; ++j) o.s[j] = tile[(toct + j) * 36 + d];
  *(bf16x8*)(vt + ((size_t)bh * 32 + d) * 512 + tt + toct) = o.v8;
}

// ---------------- persistent 256x256 GEMM, per-phase staging spread -------
// Grid MUST be 256. 8 waves (2Mx4N), per-wave C 128x64; BK=64; 2 K-tile LDS dbuf.
// m196/m201 lever: every phase interleaves {2-4 gload_lds || ds_reads || MFMA}.
// Each wave stages its 32-row slice of A(g+1) in ph1 (wid&2==0) or ph2 (else);
// its B(g+2) slice in ph3 (wid&1==0) or ph4 (else). Overwrite-safety: the region
// a stage lands in was last ds_read >=1 closed barrier earlier (af@ph1, ag@ph3,
// bfa@ph1, bfb@ph2). Cross-wave DMA visibility: each wave confirms its OWN stages
// via ONE vmcnt(4) at ph4 (drains A(g+1)+B(g+1), leaves B(g+2) in flight) before
// the SBAR that precedes the first read; tail uses vmcnt(0).
// MODE 1: QKV scatter (Q,K -> obf [2][B][H][T][D], Q scaled; V -> vout natural)
// MODE 2: out fp32 = acc + bias[col] + resid[row*N+col]
// MODE 3: out bf16 = relu(acc + bias[col])
template <int MODE, int P, int KT, int NBY>
__device__ __forceinline__ void gemm_persist(
    const unsigned short* __restrict__ A, const unsigned short* __restrict__ Bt,
    int N,
    unsigned short* __restrict__ obf, float* __restrict__ of32,
    const float* __restrict__ bias, const float* __restrict__ resid,
    unsigned short* __restrict__ vout)
{
  constexpr int K = KT * 64;
  constexpr int TOT = P * KT;
  __shared__ __align__(16) unsigned short As[2][256 * 64];
  __shared__ __align__(16) unsigned short Bs[2][256 * 64];
  const int tid = threadIdx.x, lane = tid & 63, wid = tid >> 6;
  const int wr = wid >> 2, wc = wid & 3;
  const int r = lane & 15, hq = lane >> 4;

  // XCD-chunked persistent tile list: block b -> tau0 = (b%8)*32P + (b/8)*P
  const int tau0 = (blockIdx.x & 7) * (32 * P) + (blockIdx.x >> 3) * P;

  const int srow = wid * 32 + (lane >> 3);
  const int schunk = ((lane & 7) ^ ((lane >> 3) & 7)) * 8;  // element offset in [0,64)

  auto STAGE_A = [&](int g2) {
    const int m2 = g2 / KT, kt2 = g2 % KT;
    const int bx = (tau0 + m2) / NBY;
    const unsigned short* src = A + (size_t)(bx * 256 + srow) * K + kt2 * 64 + schunk;
    char* dst = (char*)(&As[g2 & 1][0]) + wid * 4096;
#pragma unroll
    for (int g = 0; g < 4; ++g) gload_lds16(src + (size_t)g * 8 * K, dst + g * 1024);
  };
  auto STAGE_B = [&](int g2) {
    const int m2 = g2 / KT, kt2 = g2 % KT;
    const int tau = tau0 + m2;
    const int by = tau - (tau / NBY) * NBY;
    const unsigned short* src = Bt + (size_t)(by * 256 + srow) * K + kt2 * 64 + schunk;
    char* dst = (char*)(&Bs[g2 & 1][0]) + wid * 4096;
#pragma unroll
    for (int g = 0; g < 4; ++g) gload_lds16(src + (size_t)g * 8 * K, dst + g * 1024);
  };

  // ds_read addressing: byte = row*128 + ((chunk ^ (row&7))*16), chunk = kk*4+hq
  const int x0 = ((hq) ^ (r & 7)) * 16;
  const int x1 = ((4 + hq) ^ (r & 7)) * 16;
  const int abase = (wr * 128 + r) * 128;
  const int bbase = (wc * 64 + r) * 128;

  f32x4 acc[8][4] = {};
  bf16x8 af[4][2], bfa[2][2], bfb[2][2];
  const bool aPh1 = ((wid & 2) == 0);   // waves 0,1,4,5 stage A in ph1; others ph2
  const bool bPh3 = ((wid & 1) == 0);   // even waves stage B in ph3; odd in ph4

  STAGE_A(0); STAGE_B(0);
  STAGE_A(1); STAGE_B(1);
  WAITV0(); SCHED0();
  SBAR();

#pragma unroll 1
  for (int p = 0; p < P; ++p) {
#pragma unroll 2
    for (int t = 0; t < KT; ++t) {
      const int g = p * KT + t;
      const char* Ab = (const char*)(&As[g & 1][0]);
      const char* Bb = (const char*)(&Bs[g & 1][0]);
      const bool stA = (g >= 1) && (g + 1 < TOT);
      const bool stB = (g + 2 < TOT);
      // ---- ph1: stage-A group 1; read af(A0)+bfa; MFMA q(0,0)
      if (stA && aPh1) STAGE_A(g + 1);
#pragma unroll
      for (int m = 0; m < 4; ++m) {
        af[m][0] = *(const bf16x8*)(Ab + abase + m * 2048 + x0);
        af[m][1] = *(const bf16x8*)(Ab + abase + m * 2048 + x1);
      }
#pragma unroll
      for (int n = 0; n < 2; ++n) {
        bfa[n][0] = *(const bf16x8*)(Bb + bbase + n * 2048 + x0);
        bfa[n][1] = *(const bf16x8*)(Bb + bbase + n * 2048 + x1);
      }
      WAITL(0); SCHED0();
      PRIO1();
#pragma unroll
      for (int m = 0; m < 4; ++m)
#pragma unroll
        for (int n = 0; n < 2; ++n) {
          acc[m][n] = MFMA32(af[m][0], bfa[n][0], acc[m][n]);
          acc[m][n] = MFMA32(af[m][1], bfa[n][1], acc[m][n]);
        }
      PRIO0();
      SBAR();
      // ---- ph2: stage-A group 2; read bfb; MFMA q(0,1)
      if (stA && !aPh1) STAGE_A(g + 1);
#pragma unroll
      for (int n = 0; n < 2; ++n) {
        bfb[n][0] = *(const bf16x8*)(Bb + bbase + (n + 2) * 2048 + x0);
        bfb[n][1] = *(const bf16x8*)(Bb + bbase + (n + 2) * 2048 + x1);
      }
      WAITL(0); SCHED0();
      PRIO1();
#pragma unroll
      for (int m = 0; m < 4; ++m)
#pragma unroll
        for (int n = 0; n < 2; ++n) {
          acc[m][n + 2] = MFMA32(af[m][0], bfb[n][0], acc[m][n + 2]);
          acc[m][n + 2] = MFMA32(af[m][1], bfb[n][1], acc[m][n + 2]);
        }
      PRIO0();
      SBAR();
      // ---- ph3: stage-B group 1; read af<-A1 (overwrite); MFMA q(1,0)
      if (stB && bPh3) STAGE_B(g + 2);
#pragma unroll
      for (int m = 0; m < 4; ++m) {
        af[m][0] = *(const bf16x8*)(Ab + abase + 8192 + m * 2048 + x0);
        af[m][1] = *(const bf16x8*)(Ab + abase + 8192 + m * 2048 + x1);
      }
      WAITL(0); SCHED0();
      PRIO1();
#pragma unroll
      for (int m = 0; m < 4; ++m)
#pragma unroll
        for (int n = 0; n < 2; ++n) {
          acc[4 + m][n] = MFMA32(af[m][0], bfa[n][0], acc[4 + m][n]);
          acc[4 + m][n] = MFMA32(af[m][1], bfa[n][1], acc[4 + m][n]);
        }
      PRIO0();
      SBAR();
      // ---- ph4: stage-B group 2; MFMA q(1,1); confirm own stages; barrier
      if (stB && !bPh3) STAGE_B(g + 2);
      PRIO1();
#pragma unroll
      for (int m = 0; m < 4; ++m)
#pragma unroll
        for (int n = 0; n < 2; ++n) {
          acc[4 + m][n + 2] = MFMA32(af[m][0], bfb[n][0], acc[4 + m][n + 2]);
          acc[4 + m][n + 2] = MFMA32(af[m][1], bfb[n][1], acc[4 + m][n + 2]);
        }
      PRIO0();
      if (stB) { WAITVN(4); } else { WAITV0(); }
      SCHED0();
      SBAR();
    }

    // ---- macro epilogue (regs -> global only; next-macro pipeline in flight)
    {
      const int tau = tau0 + p;
      const int bx = tau / NBY, by = tau - bx * NBY;
      const int brow = bx << 8, bcol = by << 8;
#pragma unroll
      for (int m = 0; m < 8; ++m)
#pragma unroll
        for (int n = 0; n < 4; ++n) {
          const int row0 = brow + wr * 128 + m * 16 + hq * 4;
          const int col = bcol + wc * 64 + n * 16 + r;
#pragma unroll
          for (int q2 = 0; q2 < 4; ++q2) {
            const int row = row0 + q2;
            float v = acc[m][n][q2];
            if (MODE == 1) {
              const int which = col >> 9, hh = (col >> 5) & 15, dd = col & 31;
              const int bb = row >> 9, tt = row & 511;
              const size_t off = ((((size_t)bb) * 16 + hh) * 512 + tt) * 32 + dd;
              if (which < 2) {
                if (which == 0) v *= 0.25503521f;  // (1/sqrt(32)) * log2(e)
                obf[(size_t)which * 16777216 + off] = f2bf(v);
              } else
                vout[off] = f2bf(v);
            } else if (MODE == 2) {
              v += bias[col] + resid[(size_t)row * N + col];
              of32[(size_t)row * N + col] = v;
            } else if (MODE == 3) {
              v = fmaxf(v + bias[col], 0.f);
              obf[(size_t)row * N + col] = f2bf(v);
            }
            acc[m][n][q2] = 0.f;
          }
        }
    }
  }
}

// distinct names per call site for rocprof attribution; grid must be 256
__global__ __launch_bounds__(512, 2) void qkv_gemm(
    const unsigned short* __restrict__ A, const unsigned short* __restrict__ Bt,
    unsigned short* __restrict__ obf, unsigned short* __restrict__ vout)
{ gemm_persist<1, 3, 8, 6>(A, Bt, 1536, obf, nullptr, nullptr, nullptr, vout); }

__global__ __launch_bounds__(512, 2) void proj_gemm(
    const unsigned short* __restrict__ A, const unsigned short* __restrict__ Bt,
    float* __restrict__ of32, const float* __restrict__ bias,
    const float* __restrict__ resid)
{ gemm_persist<2, 1, 8, 2>(A, Bt, 512, nullptr, of32, bias, resid, nullptr); }

__global__ __launch_bounds__(512, 2) void ffn1_gemm(
    const unsigned short* __restrict__ A, const unsigned short* __restrict__ Bt,
    unsigned short* __restrict__ obf, const float* __restrict__ bias)
{ gemm_persist<3, 4, 8, 8>(A, Bt, 2048, obf, nullptr, bias, nullptr, nullptr); }

__global__ __launch_bounds__(512, 2) void ffn2_gemm(
    const unsigned short* __restrict__ A, const unsigned short* __restrict__ Bt,
    float* __restrict__ of32, const float* __restrict__ bias,
    const float* __restrict__ resid)
{ gemm_persist<2, 1, 32, 2>(A, Bt, 512, nullptr, of32, bias, resid, nullptr); }

// ---------------- causal attention: one block per (b,h), 8 waves ----------------
// Swapped QK^T: S^T = mfma(K_frag, Q_frag) so each lane owns one q-column with
// keys lane-local (k = 4*hq + j per 16-key tile). Softmax: in-lane tree + 2 shfl_xor.
// P feeds PV (16x16x16 MFMA) directly via cvt_pk -> no LDS round-trip.
// Scores arrive pre-scaled by (1/sqrt(32))*log2(e); exp = v_exp_f32 (2^x).
// Qb,Kb: [B][H][T][D] bf16 ; Vt: [B][H][D][T] bf16 ; att: [B*T][512] bf16 (col h*32+d)
__global__ __launch_bounds__(512, 4) void attn_kernel(
    const unsigned short* __restrict__ Qb, const unsigned short* __restrict__ Kb,
    const unsigned short* __restrict__ Vt, unsigned short* __restrict__ att)
{
  __shared__ __align__(16) unsigned short Ks[512 * 32];  // 32 KB, linear [t][d]
  __shared__ __align__(16) unsigned short Vs[32 * 512];  // 32 KB, [d][t], 16B-blk ^ (d&15)
  const int tid = threadIdx.x, lane = tid & 63, wid = tid >> 6;
  const int bh = blockIdx.x;
  const int r = lane & 15, hq = lane >> 4;
  const unsigned short* Kg = Kb + (size_t)bh * (512 * 32);
  const unsigned short* Vg = Vt + (size_t)bh * (32 * 512);
#pragma unroll
  for (int it = 0; it < 4; ++it) {
    const int c = it * 512 + tid;
    gload_lds16(Kg + c * 8, (char*)Ks + (it * 512 + wid * 64) * 16);
    const int d = c >> 6, sb = c & 63;
    gload_lds16(Vg + d * 512 + (sb ^ (d & 15)) * 8, (char*)Vs + (it * 512 + wid * 64) * 16);
  }
  __syncthreads();

  const f32x4 z = {0.f, 0.f, 0.f, 0.f};
  for (int p = 0; p < 4; ++p) {
    // balanced triangular tile pairing: waves get tiles {w, 15-w, 16+w, 31-w}
    const int t0 = (((p >> 1) << 4) + ((p & 1) ? 15 - wid : wid)) << 4;
    const bf16x8 qf = *(const bf16x8*)(Qb + ((size_t)bh * 512 + t0 + r) * 32 + hq * 8);
    f32x4 o0 = z, o1 = z;
    float m = -1e30f, l = 0.f;
    const int s0m = t0 & ~31;
    for (int s0 = 0; s0 <= s0m; s0 += 32) {
      f32x4 st0 = MFMA32(*(const bf16x8*)((const char*)Ks + (s0 + r) * 64 + hq * 16), qf, z);
      f32x4 st1 = MFMA32(*(const bf16x8*)((const char*)Ks + (s0 + 16 + r) * 64 + hq * 16), qf, z);
      if (s0 == s0m) {                       // only the diagonal chunk needs masking
        const int qq = t0 + r;
#pragma unroll
        for (int j = 0; j < 4; ++j) {
          if (s0 + 4 * hq + j > qq)      st0[j] = -1e30f;
          if (s0 + 16 + 4 * hq + j > qq) st1[j] = -1e30f;
        }
      }
      float mx = fmaxf(fmaxf(fmaxf(st0[0], st0[1]), fmaxf(st0[2], st0[3])),
                       fmaxf(fmaxf(st1[0], st1[1]), fmaxf(st1[2], st1[3])));
      mx = fmaxf(mx, __shfl_xor(mx, 16));
      mx = fmaxf(mx, __shfl_xor(mx, 32));
      if (!__all(mx <= m + 8.f)) {           // defer-max (T13), THR=8 in log2 domain
        const float mn = fmaxf(m, mx);
        const float f = exp2fast(m - mn);
        m = mn; l *= f; o0 *= f; o1 *= f;
      }
      float p0[4], p1[4];
#pragma unroll
      for (int j = 0; j < 4; ++j) {
        p0[j] = exp2fast(st0[j] - m);
        p1[j] = exp2fast(st1[j] - m);
      }
      float rs = ((p0[0] + p0[1]) + (p0[2] + p0[3])) + ((p1[0] + p1[1]) + (p1[2] + p1[3]));
      rs += __shfl_xor(rs, 16);
      rs += __shfl_xor(rs, 32);
      l += rs;
      union { unsigned u[2]; bf16x4 v; } a0, a1;
      a0.u[0] = cvtpk(p0[0], p0[1]); a0.u[1] = cvtpk(p0[2], p0[3]);
      a1.u[0] = cvtpk(p1[0], p1[1]); a1.u[1] = cvtpk(p1[2], p1[3]);
      const int lb = (s0 >> 3) + (hq >> 1);
      const char* vb = (const char*)Vs + (hq & 1) * 8;
      o0 = MFMA16(a0.v, *(const bf16x4*)(vb + r * 1024 + ((lb) ^ r) * 16), o0);
      o0 = MFMA16(a1.v, *(const bf16x4*)(vb + r * 1024 + ((lb + 2) ^ r) * 16), o0);
      o1 = MFMA16(a0.v, *(const bf16x4*)(vb + (r + 16) * 1024 + ((lb) ^ r) * 16), o1);
      o1 = MFMA16(a1.v, *(const bf16x4*)(vb + (r + 16) * 1024 + ((lb + 2) ^ r) * 16), o1);
    }
    // O ownership: d = r (o0) / 16+r (o1), q = t0 + 4*hq + j. l lives on lanes keyed by
    // r == q_rel (all 4 hq copies equal after the xor-reduce) -> shfl to fetch.
    const size_t ob = ((size_t)(bh >> 4) * 512) * 512 + (size_t)((bh & 15) * 32);
#pragma unroll
    for (int j = 0; j < 4; ++j) {
      const float li = 1.f / __shfl(l, 4 * hq + j);
      const size_t rowb = ob + (size_t)(t0 + 4 * hq + j) * 512;
      att[rowb + r]      = f2bf(o0[j] * li);
      att[rowb + 16 + r] = f2bf(o1[j] * li);
    }
  }
}

// ---------------- launcher ----------------
extern "C" void kernel_launch(void* const* d_in, const int* in_sizes, int n_in,
                              void* d_out, int out_size, void* d_ws, size_t ws_size,
                              hipStream_t stream)
{
  const float* x   = (const float*)d_in[0];
  const float* Wq  = (const float*)d_in[1];
  const float* Wk  = (const float*)d_in[2];
  const float* Wv  = (const float*)d_in[3];
  const float* Wp  = (const float*)d_in[4];
  const float* bp  = (const float*)d_in[5];
  const float* W1  = (const float*)d_in[6];
  const float* b1  = (const float*)d_in[7];
  const float* W2  = (const float*)d_in[8];
  const float* b2  = (const float*)d_in[9];
  const float* g1  = (const float*)d_in[10];
  const float* bb1 = (const float*)d_in[11];
  const float* g2  = (const float*)d_in[12];
  const float* bb2 = (const float*)d_in[13];
  float* out = (float*)d_out;

  char* ws = (char*)d_ws;
  // layout (bytes):
  unsigned short* h    = (unsigned short*)(ws);               // 32 MB (h, then reused as h2)
  unsigned short* wqkv = (unsigned short*)(ws + 33554432);    // 1.5 MB (1536 x 512)
  unsigned short* wp   = (unsigned short*)(ws + 35127296);    // 0.5 MB (512 x 512)
  unsigned short* w1   = (unsigned short*)(ws + 35651584);    // 2 MB (2048 x 512)
  unsigned short* w2   = (unsigned short*)(ws + 37748736);    // 2 MB (512 x 2048)
  unsigned short* qk   = (unsigned short*)(ws + 39845888);    // 64 MB: Q then K [B][H][T][D]
  unsigned short* vt   = qk + (size_t)2 * 16777216;           // 32 MB: V^T [B][H][D][T]
  unsigned short* att  = vt + 16777216;                       // 32 MB: attn out / V-natural
  unsigned short* vnat = att;                                 // V [B][H][T][D] staging
  unsigned short* mid  = qk;                                  // 128 MB alias over qk+vt+att
  if (ws_size < 174063616) return;  // insufficient workspace -> visible failure

  prep_qkv_w<<<384, 256, 0, stream>>>(Wq, Wk, Wv, wqkv);
  transpose_cast<<<64, 256, 0, stream>>>(Wp, wp, 512, 512);
  transpose_cast<<<256, 256, 0, stream>>>(W1, w1, 512, 2048);
  transpose_cast<<<256, 256, 0, stream>>>(W2, w2, 2048, 512);

  ln_kernel<<<8192, 256, 0, stream>>>(x, g1, bb1, h);

  qkv_gemm<<<256, 512, 0, stream>>>(h, wqkv, qk, vnat);

  vt_kernel<<<8192, 256, 0, stream>>>(vnat, vt);

  attn_kernel<<<1024, 512, 0, stream>>>(qk, qk + 16777216, vt, att);

  proj_gemm<<<256, 512, 0, stream>>>(att, wp, out, bp, x);

  ln_kernel<<<8192, 256, 0, stream>>>(out, g2, bb2, h);

  ffn1_gemm<<<256, 512, 0, stream>>>(h, w1, mid, b1);

  ffn2_gemm<<<256, 512, 0, stream>>>(mid, w2, out, b2, out);
}